// Round 7
// baseline (4773.957 us; speedup 1.0000x reference)
//
#include <hip/hip_runtime.h>
#include <hip/hip_fp16.h>
#include <cstdint>

#define BATCH 256
#define SEQ   2048
#define IN_DIM 4
#define HID   256
#define G4    1024   // 4*HID

// ---------- helpers ----------

typedef _Float16 h2_t __attribute__((ext_vector_type(2)));

union U32H2 { uint32_t u; h2_t h; __half2 hh; };

__device__ __forceinline__ float fdot2(uint32_t w, uint32_t h, float acc) {
    U32H2 a; a.u = w; U32H2 b; b.u = h;
    return __builtin_amdgcn_fdot2(a.h, b.h, acc, false);
}

__device__ __forceinline__ uint32_t pack_h2(float a, float b) {
    U32H2 u; u.hh = __floats2half2_rn(a, b); return u.u;
}

__device__ __forceinline__ float sigmoidf_(float x) {
    return 1.0f / (1.0f + __expf(-x));
}
__device__ __forceinline__ float tanhf_(float x) {
    return 1.0f - 2.0f / (__expf(2.0f * x) + 1.0f);
}

// ---------- ws layout (bytes) ----------
#define OFF_WTAIL 393216
#define OFF_BIAS  524288
#define OFF_CONVF 528384
#define OFF_KSIM  529408
#define OFF_HOUT  530432
#define OFF_WIHP  792576

// ---------- prep: fp16 conversion + bias fuse ----------
__global__ void prep_kernel(const float* __restrict__ Whh,
                            const float* __restrict__ Wih,
                            const float* __restrict__ bih,
                            const float* __restrict__ bhh,
                            uint32_t* __restrict__ wreg,
                            uint32_t* __restrict__ wtail,
                            float* __restrict__ bias,
                            uint32_t* __restrict__ wihp) {
    int gid = blockIdx.x * blockDim.x + threadIdx.x;  // 0..131071
    int row = gid >> 7;      // 0..1023
    int pr  = gid & 127;     // pair index, cols 2pr, 2pr+1
    float a = Whh[row * HID + 2 * pr];
    float b = Whh[row * HID + 2 * pr + 1];
    uint32_t p = pack_h2(a, b);
    if (pr < 96) {
        wreg[pr * G4 + row] = p;
    } else {
        int q = pr - 96;            // 0..31
        int c = q >> 2, d = q & 3;  // uint4 chunk 0..7, dword 0..3
        wtail[(c * G4 + row) * 4 + d] = p;
    }
    if (gid < G4) {
        bias[gid] = bih[gid] + bhh[gid];
        wihp[gid * 2 + 0] = pack_h2(Wih[gid * 4 + 0], Wih[gid * 4 + 1]);
        wihp[gid * 2 + 1] = pack_h2(Wih[gid * 4 + 2], Wih[gid * 4 + 3]);
    }
}

// ---------- features: conv mean + RBF kernel sim ----------
__global__ void feat_kernel(const float* __restrict__ x,
                            const float* __restrict__ conv_w,
                            const float* __restrict__ conv_b,
                            float* __restrict__ convf,
                            float* __restrict__ ksim) {
    int b = blockIdx.x, t = threadIdx.x;  // 256 threads
    const float4* xb = (const float4*)(x + (size_t)b * SEQ * IN_DIM);
    float cw0 = conv_w[0], cw1 = conv_w[1], cw2 = conv_w[2], cw3 = conv_w[3];
    float cb = conv_b[0];
    float s_sig = 0.f, s_sq = 0.f;
#pragma unroll
    for (int k = 0; k < 8; ++k) {
        int s = t + k * 256;
        float4 v = xb[s];
        float d = v.x * cw0 + v.y * cw1 + v.z * cw2 + v.w * cw3 + cb;
        s_sig += sigmoidf_(d);
        s_sq  += v.x * v.x + v.y * v.y + v.z * v.z + v.w * v.w;
    }
    __shared__ float sA[256], sB[256];
    sA[t] = s_sig; sB[t] = s_sq;
    __syncthreads();
    for (int off = 128; off > 0; off >>= 1) {
        if (t < off) { sA[t] += sA[t + off]; sB[t] += sB[t + off]; }
        __syncthreads();
    }
    if (t == 0) {
        convf[b] = sA[0] * (1.0f / 2048.0f);
        ksim[b]  = __expf(-sB[0]);
    }
}

// ---------- macro machinery: 96 named scalar weight pairs (ONE row) ----------
#define REP96(F) \
F(0)F(1)F(2)F(3)F(4)F(5)F(6)F(7)F(8)F(9) \
F(10)F(11)F(12)F(13)F(14)F(15)F(16)F(17)F(18)F(19) \
F(20)F(21)F(22)F(23)F(24)F(25)F(26)F(27)F(28)F(29) \
F(30)F(31)F(32)F(33)F(34)F(35)F(36)F(37)F(38)F(39) \
F(40)F(41)F(42)F(43)F(44)F(45)F(46)F(47)F(48)F(49) \
F(50)F(51)F(52)F(53)F(54)F(55)F(56)F(57)F(58)F(59) \
F(60)F(61)F(62)F(63)F(64)F(65)F(66)F(67)F(68)F(69) \
F(70)F(71)F(72)F(73)F(74)F(75)F(76)F(77)F(78)F(79) \
F(80)F(81)F(82)F(83)F(84)F(85)F(86)F(87)F(88)F(89) \
F(90)F(91)F(92)F(93)F(94)F(95)

#define WLOAD(i) uint32_t w_##i = wreg[(i) * G4 + r];
#define WPIN(i)  asm("" : "+v"(w_##i));

// lane L provides h-pairs C0=2L (hp.x) and C1=2L+1 (hp.y); 1 row, 2 acc chains
#define LANE(L, C0, C1) { \
    const uint32_t sx_ = (uint32_t)__builtin_amdgcn_readlane((int)hp.x, L); \
    const uint32_t sy_ = (uint32_t)__builtin_amdgcn_readlane((int)hp.y, L); \
    a  = fdot2(w_##C0, sx_, a); \
    ab = fdot2(w_##C1, sy_, ab); }

// tail chunk C: pair-cols 96+4C..99+4C from LDS; h-dwords from lanes 48+2C, 49+2C
#define TAILC(C) { \
    const uint4 wt_ = tail4_r[(C) * G4]; \
    const uint32_t s0_ = (uint32_t)__builtin_amdgcn_readlane((int)hp.x, 48 + 2 * (C)); \
    const uint32_t s1_ = (uint32_t)__builtin_amdgcn_readlane((int)hp.y, 48 + 2 * (C)); \
    const uint32_t s2_ = (uint32_t)__builtin_amdgcn_readlane((int)hp.x, 49 + 2 * (C)); \
    const uint32_t s3_ = (uint32_t)__builtin_amdgcn_readlane((int)hp.y, 49 + 2 * (C)); \
    a  = fdot2(wt_.x, s0_, a); \
    ab = fdot2(wt_.y, s1_, ab); \
    a  = fdot2(wt_.z, s2_, a); \
    ab = fdot2(wt_.w, s3_, ab); }

// ---------- LSTM recurrence: 1 sample per block, 1024 threads, 1 row/thread --
// Thread t owns gate-row r=t (torch order: rows 0-255=i, 256-511=f, 512-767=g,
// 768-1023=o). Per step each thread computes z_r -> LDS zbuf; after barrier,
// threads u<256 combine the 4 gate rows, update c_u, write fp16 h_u.
//
// R7 key change: STATIC __shared__ (133 KB). R1-R6 used dynamic LDS, which is
// invisible to the backend's occupancy model -> it assumed LDS=0, priced
// registers for 8 waves/EU (VGPR=64 in R6 despite a free 128 budget), and
// streamed the weights from L2 every step (~3000 cyc/step = the wall).
// Static LDS makes 1 WG/CU visible at compile time -> 4 waves/EU -> 128-VGPR
// budget >= the ~118 live set of this 1-row/thread design.
#define TAIL_DW (8 * 1024 * 4)

__shared__ uint32_t s_tail[TAIL_DW];   // 131072 B
__shared__ uint32_t s_hbuf[256];       // two 128-dword h buffers (fp16 x256 each)
__shared__ float    s_zbuf[1024];      // 4096 B

__global__ __launch_bounds__(1024, 4)
__attribute__((amdgpu_waves_per_eu(4, 4)))
void recur_kernel(const float* __restrict__ x,
                  const uint32_t* __restrict__ wihp,
                  const uint32_t* __restrict__ wreg,
                  const uint32_t* __restrict__ wtail,
                  const float* __restrict__ bias,
                  float* __restrict__ h_out) {
    const int b = blockIdx.x;
    const int t = threadIdx.x;
    const int lane = t & 63;
    const int r = t;

    // stage w-tail into LDS (coalesced, layout identical)
    {
        const uint4* src = (const uint4*)wtail;
        uint4* dst = (uint4*)s_tail;
#pragma unroll
        for (int i = 0; i < 8; ++i) dst[t + i * 1024] = src[t + i * 1024];
    }
    if (t < 128) s_hbuf[t] = 0u;  // h = 0 (fp16 zeros)

    // 96 named scalar weight registers (pair-cols 0..95 of row r)
    REP96(WLOAD)
    REP96(WPIN)

    const uint2 wih = ((const uint2*)wihp)[r];  // fp16-packed Wih row (2 dwords)
    const float bias_r = bias[r];

    float c_state = 0.f;
    float h_last = 0.f;
    const float4* xb = (const float4*)(x + (size_t)b * SEQ * IN_DIM);
    const uint4* tail4_r = (const uint4*)s_tail + r;   // + C*G4 per chunk

    __syncthreads();

    uint32_t* hr = s_hbuf;
    uint32_t* hw = s_hbuf + 128;

    for (int s = 0; s < SEQ; ++s) {
        // zero-cost: keeps all 96 weights loop-carried in VGPRs
        REP96(WPIN)

        const float4 xt = xb[s];
        const uint32_t xh0 = pack_h2(xt.x, xt.y);
        const uint32_t xh1 = pack_h2(xt.z, xt.w);
        float a  = fdot2(wih.x, xh0, bias_r);
        float ab = fdot2(wih.y, xh1, 0.f);

        // one lane-distributed read: lane L holds h-dwords 2L, 2L+1
        const uint2 hp = ((const uint2*)hr)[lane];

        LANE(0,0,1)   LANE(1,2,3)   LANE(2,4,5)   LANE(3,6,7)
        LANE(4,8,9)   LANE(5,10,11) LANE(6,12,13) LANE(7,14,15)
        LANE(8,16,17) LANE(9,18,19) LANE(10,20,21) LANE(11,22,23)
        LANE(12,24,25) LANE(13,26,27) LANE(14,28,29) LANE(15,30,31)
        LANE(16,32,33) LANE(17,34,35) LANE(18,36,37) LANE(19,38,39)
        LANE(20,40,41) LANE(21,42,43) LANE(22,44,45) LANE(23,46,47)
        LANE(24,48,49) LANE(25,50,51) LANE(26,52,53) LANE(27,54,55)
        LANE(28,56,57) LANE(29,58,59) LANE(30,60,61) LANE(31,62,63)
        LANE(32,64,65) LANE(33,66,67) LANE(34,68,69) LANE(35,70,71)
        LANE(36,72,73) LANE(37,74,75) LANE(38,76,77) LANE(39,78,79)
        LANE(40,80,81) LANE(41,82,83) LANE(42,84,85) LANE(43,86,87)
        LANE(44,88,89) LANE(45,90,91) LANE(46,92,93) LANE(47,94,95)

        TAILC(0) TAILC(1) TAILC(2) TAILC(3)
        TAILC(4) TAILC(5) TAILC(6) TAILC(7)

        s_zbuf[t] = a + ab;
        __syncthreads();

        if (t < 256) {
            const float zi = s_zbuf[t];
            const float zf = s_zbuf[t + 256];
            const float zg = s_zbuf[t + 512];
            const float zo = s_zbuf[t + 768];
            c_state = sigmoidf_(zf) * c_state + sigmoidf_(zi) * tanhf_(zg);
            h_last = sigmoidf_(zo) * tanhf_(c_state);
            ((__half*)hw)[t] = __float2half_rn(h_last);
        }
        __syncthreads();
        uint32_t* tmp = hr; hr = hw; hw = tmp;
    }

    if (t < 256) h_out[b * HID + t] = h_last;
}

// ---------- head: fc + relu + out + softmax ----------
__global__ void head_kernel(const float* __restrict__ fc_w,
                            const float* __restrict__ fc_b,
                            const float* __restrict__ out_w,
                            const float* __restrict__ out_b,
                            const float* __restrict__ convf,
                            const float* __restrict__ ksim,
                            const float* __restrict__ h_out,
                            float* __restrict__ out) {
    int b = blockIdx.x, j = threadIdx.x;  // 256 threads
    const float* hrow = h_out + b * HID;
    const float* w = fc_w + j * (HID + 2);
    float acc = fc_b[j] + w[0] * convf[b] + w[HID + 1] * ksim[b];
#pragma unroll 8
    for (int k = 0; k < HID; ++k) acc += w[1 + k] * hrow[k];
    float hid = fmaxf(acc, 0.f);
    __shared__ float r0[256], r1[256];
    r0[j] = hid * out_w[j];
    r1[j] = hid * out_w[HID + j];
    __syncthreads();
    for (int off = 128; off > 0; off >>= 1) {
        if (j < off) { r0[j] += r0[j + off]; r1[j] += r1[j + off]; }
        __syncthreads();
    }
    if (j == 0) {
        float l0 = r0[0] + out_b[0];
        float l1 = r1[0] + out_b[1];
        float m = fmaxf(l0, l1);
        float e0 = __expf(l0 - m), e1 = __expf(l1 - m);
        float inv = 1.0f / (e0 + e1);
        out[b * 2 + 0] = e0 * inv;
        out[b * 2 + 1] = e1 * inv;
    }
}

// ---------- launch ----------
extern "C" void kernel_launch(void* const* d_in, const int* in_sizes, int n_in,
                              void* d_out, int out_size, void* d_ws, size_t ws_size,
                              hipStream_t stream) {
    const float* x      = (const float*)d_in[0];
    const float* conv_w = (const float*)d_in[1];
    const float* conv_b = (const float*)d_in[2];
    const float* Wih    = (const float*)d_in[3];
    const float* Whh    = (const float*)d_in[4];
    const float* bih    = (const float*)d_in[5];
    const float* bhh    = (const float*)d_in[6];
    const float* fcw    = (const float*)d_in[7];
    const float* fcb    = (const float*)d_in[8];
    const float* outw   = (const float*)d_in[9];
    const float* outb   = (const float*)d_in[10];
    float* out = (float*)d_out;

    uint8_t* ws = (uint8_t*)d_ws;
    uint32_t* wreg  = (uint32_t*)ws;
    uint32_t* wtail = (uint32_t*)(ws + OFF_WTAIL);
    float* bias  = (float*)(ws + OFF_BIAS);
    float* convf = (float*)(ws + OFF_CONVF);
    float* ksim  = (float*)(ws + OFF_KSIM);
    float* h_out = (float*)(ws + OFF_HOUT);
    uint32_t* wihp = (uint32_t*)(ws + OFF_WIHP);

    prep_kernel<<<512, 256, 0, stream>>>(Whh, Wih, bih, bhh, wreg, wtail, bias, wihp);
    feat_kernel<<<BATCH, 256, 0, stream>>>(x, conv_w, conv_b, convf, ksim);

    recur_kernel<<<BATCH, 1024, 0, stream>>>(x, wihp, wreg, wtail, bias, h_out);

    head_kernel<<<BATCH, 256, 0, stream>>>(fcw, fcb, outw, outb, convf, ksim, h_out, out);
}

// Round 11
// 4091.834 us; speedup vs baseline: 1.1667x; 1.1667x over previous
//
#include <hip/hip_runtime.h>
#include <hip/hip_fp16.h>
#include <cstdint>

#define BATCH 256
#define SEQ   2048
#define IN_DIM 4
#define HID   256
#define G4    1024   // 4*HID

// ---------- helpers ----------

typedef _Float16 h2_t __attribute__((ext_vector_type(2)));

union U32H2 { uint32_t u; h2_t h; __half2 hh; };

__device__ __forceinline__ float fdot2(uint32_t w, uint32_t h, float acc) {
    U32H2 a; a.u = w; U32H2 b; b.u = h;
    return __builtin_amdgcn_fdot2(a.h, b.h, acc, false);
}

__device__ __forceinline__ uint32_t pack_h2(float a, float b) {
    U32H2 u; u.hh = __floats2half2_rn(a, b); return u.u;
}

__device__ __forceinline__ float sigmoidf_(float x) {
    return 1.0f / (1.0f + __expf(-x));
}
__device__ __forceinline__ float tanhf_(float x) {
    return 1.0f - 2.0f / (__expf(2.0f * x) + 1.0f);
}

// ---------- ws layout (bytes) ----------
#define OFF_WTAIL 393216
#define OFF_BIAS  524288
#define OFF_CONVF 528384
#define OFF_KSIM  529408
#define OFF_HOUT  530432

// ---------- prep: fp16 conversion + bias fuse ----------
__global__ void prep_kernel(const float* __restrict__ Whh,
                            const float* __restrict__ bih,
                            const float* __restrict__ bhh,
                            uint32_t* __restrict__ wreg,
                            uint32_t* __restrict__ wtail,
                            float* __restrict__ bias) {
    int gid = blockIdx.x * blockDim.x + threadIdx.x;  // 0..131071
    int row = gid >> 7;      // 0..1023
    int pr  = gid & 127;     // pair index, cols 2pr, 2pr+1
    float a = Whh[row * HID + 2 * pr];
    float b = Whh[row * HID + 2 * pr + 1];
    uint32_t p = pack_h2(a, b);
    if (pr < 96) {
        wreg[pr * G4 + row] = p;
    } else {
        int q = pr - 96;            // 0..31
        int c = q >> 2, d = q & 3;  // uint4 chunk 0..7, dword 0..3
        wtail[(c * G4 + row) * 4 + d] = p;
    }
    if (gid < G4) bias[gid] = bih[gid] + bhh[gid];
}

// ---------- features: conv mean + RBF kernel sim ----------
__global__ void feat_kernel(const float* __restrict__ x,
                            const float* __restrict__ conv_w,
                            const float* __restrict__ conv_b,
                            float* __restrict__ convf,
                            float* __restrict__ ksim) {
    int b = blockIdx.x, t = threadIdx.x;  // 256 threads
    const float4* xb = (const float4*)(x + (size_t)b * SEQ * IN_DIM);
    float cw0 = conv_w[0], cw1 = conv_w[1], cw2 = conv_w[2], cw3 = conv_w[3];
    float cb = conv_b[0];
    float s_sig = 0.f, s_sq = 0.f;
#pragma unroll
    for (int k = 0; k < 8; ++k) {
        int s = t + k * 256;
        float4 v = xb[s];
        float d = v.x * cw0 + v.y * cw1 + v.z * cw2 + v.w * cw3 + cb;
        s_sig += sigmoidf_(d);
        s_sq  += v.x * v.x + v.y * v.y + v.z * v.z + v.w * v.w;
    }
    __shared__ float sA[256], sB[256];
    sA[t] = s_sig; sB[t] = s_sq;
    __syncthreads();
    for (int off = 128; off > 0; off >>= 1) {
        if (t < off) { sA[t] += sA[t + off]; sB[t] += sB[t + off]; }
        __syncthreads();
    }
    if (t == 0) {
        convf[b] = sA[0] * (1.0f / 2048.0f);
        ksim[b]  = __expf(-sB[0]);
    }
}

// ---------- macro machinery: 96 named scalar weight pairs x 2 rows ----------
#define REP96(F) \
F(0)F(1)F(2)F(3)F(4)F(5)F(6)F(7)F(8)F(9) \
F(10)F(11)F(12)F(13)F(14)F(15)F(16)F(17)F(18)F(19) \
F(20)F(21)F(22)F(23)F(24)F(25)F(26)F(27)F(28)F(29) \
F(30)F(31)F(32)F(33)F(34)F(35)F(36)F(37)F(38)F(39) \
F(40)F(41)F(42)F(43)F(44)F(45)F(46)F(47)F(48)F(49) \
F(50)F(51)F(52)F(53)F(54)F(55)F(56)F(57)F(58)F(59) \
F(60)F(61)F(62)F(63)F(64)F(65)F(66)F(67)F(68)F(69) \
F(70)F(71)F(72)F(73)F(74)F(75)F(76)F(77)F(78)F(79) \
F(80)F(81)F(82)F(83)F(84)F(85)F(86)F(87)F(88)F(89) \
F(90)F(91)F(92)F(93)F(94)F(95)

#define WLOAD(i) uint32_t w1_##i = wreg[(i) * G4 + r1]; \
                 uint32_t w2_##i = wreg[(i) * G4 + r2];
#define WPIN(i)  asm("" : "+v"(w1_##i), "+v"(w2_##i));

// lane L provides h-pairs C0=2L (hp.x) and C1=2L+1 (hp.y); 2 rows, 4 acc chains
#define LANE(L, C0, C1) { \
    const uint32_t sx_ = (uint32_t)__builtin_amdgcn_readlane((int)hp.x, L); \
    const uint32_t sy_ = (uint32_t)__builtin_amdgcn_readlane((int)hp.y, L); \
    a1  = fdot2(w1_##C0, sx_, a1);  a2  = fdot2(w2_##C0, sx_, a2); \
    a1b = fdot2(w1_##C1, sy_, a1b); a2b = fdot2(w2_##C1, sy_, a2b); }

// tail chunk C: pair-cols 96+4C..99+4C from LDS; h from lanes 48+2C, 49+2C
#define TAILC(C) { \
    const uint4 wt1_ = tail4_1[(C) * G4]; \
    const uint4 wt2_ = tail4_2[(C) * G4]; \
    const uint32_t s0_ = (uint32_t)__builtin_amdgcn_readlane((int)hp.x, 48 + 2 * (C)); \
    const uint32_t s1_ = (uint32_t)__builtin_amdgcn_readlane((int)hp.y, 48 + 2 * (C)); \
    const uint32_t s2_ = (uint32_t)__builtin_amdgcn_readlane((int)hp.x, 49 + 2 * (C)); \
    const uint32_t s3_ = (uint32_t)__builtin_amdgcn_readlane((int)hp.y, 49 + 2 * (C)); \
    a1  = fdot2(wt1_.x, s0_, a1);  a2  = fdot2(wt2_.x, s0_, a2); \
    a1b = fdot2(wt1_.y, s1_, a1b); a2b = fdot2(wt2_.y, s1_, a2b); \
    a1  = fdot2(wt1_.z, s2_, a1);  a2  = fdot2(wt2_.z, s2_, a2); \
    a1b = fdot2(wt1_.w, s3_, a1b); a2b = fdot2(wt2_.w, s3_, a2b); }

// ---------- LSTM recurrence: 1 sample per block, 512 threads, 2 rows/thread --
// Thread t owns gate rows r1=t and r2=t+512:
//  t<256  : (i_u, g_u), u=t      -> p = sigmoid(i)*tanh(g) into pbuf
//  t>=256 : (f_u, o_u), u=t-256  -> owns c_u, computes h_u
//
// R11: __launch_bounds__(512, 1). The blocks-interpretation of the 2nd arg
// fits R3/R6/R7's measured VGPR exactly (R3 (512,2)->budget 128->124;
// R6/R7 (1024,4)->budget 64->64). (512,1) -> 1 block/CU -> 8 waves -> 2
// waves/EU -> budget 256 >= the ~220 live set (192 named weight scalars +
// working). Unlike the (1024,1) attempts (3x container failure), a 512-thread
// block is launchable under EITHER interpretation. Static LDS (R7 lesson:
// visible to the backend occupancy model). #pragma unroll 1 on the SEQ loop.
#define TAIL_DW (8 * 1024 * 4)

__global__ __launch_bounds__(512, 1)
void recur_kernel(const float* __restrict__ x,
                  const float* __restrict__ Wih,
                  const uint32_t* __restrict__ wreg,
                  const uint32_t* __restrict__ wtail,
                  const float* __restrict__ bias,
                  float* __restrict__ h_out) {
    __shared__ uint32_t s_tail[TAIL_DW];   // 131072 B
    __shared__ uint32_t s_hbuf[256];       // two 128-dword h buffers (fp16 x256)
    __shared__ float    s_pbuf[256];       // 1024 B

    const int b = blockIdx.x;
    const int t = threadIdx.x;
    const int lane = t & 63;
    const int r1 = t, r2 = t + 512;

    // stage w-tail into LDS (coalesced, layout identical)
    {
        const uint4* src = (const uint4*)wtail;
        uint4* dst = (uint4*)s_tail;
#pragma unroll
        for (int i = 0; i < 16; ++i) dst[t + i * 512] = src[t + i * 512];
    }
    if (t < 128) s_hbuf[t] = 0u;  // h = 0 (fp16 zeros)

    // 192 named scalar weight registers (pair-cols 0..95 of rows r1, r2)
    REP96(WLOAD)
    REP96(WPIN)

    const float4 wih1 = ((const float4*)Wih)[r1];
    const float4 wih2 = ((const float4*)Wih)[r2];
    const float bias1 = bias[r1], bias2 = bias[r2];

    float c_state = 0.f;
    float h_last = 0.f;
    const float4* xb = (const float4*)(x + (size_t)b * SEQ * IN_DIM);
    const uint4* tail4_1 = (const uint4*)s_tail + r1;   // + C*G4 per chunk
    const uint4* tail4_2 = (const uint4*)s_tail + r2;

    __syncthreads();

    uint32_t* hr = s_hbuf;
    uint32_t* hw = s_hbuf + 128;

#pragma unroll 1
    for (int s = 0; s < SEQ; ++s) {
        // zero-cost: keeps all 192 weights loop-carried in VGPRs
        REP96(WPIN)

        const float4 xt = xb[s];
        float a1  = bias1 + xt.x * wih1.x + xt.y * wih1.y + xt.z * wih1.z + xt.w * wih1.w;
        float a2  = bias2 + xt.x * wih2.x + xt.y * wih2.y + xt.z * wih2.z + xt.w * wih2.w;
        float a1b = 0.f, a2b = 0.f;

        // one lane-distributed read: lane L holds h-dwords 2L, 2L+1
        const uint2 hp = ((const uint2*)hr)[lane];

        LANE(0,0,1)   LANE(1,2,3)   LANE(2,4,5)   LANE(3,6,7)
        LANE(4,8,9)   LANE(5,10,11) LANE(6,12,13) LANE(7,14,15)
        LANE(8,16,17) LANE(9,18,19) LANE(10,20,21) LANE(11,22,23)
        LANE(12,24,25) LANE(13,26,27) LANE(14,28,29) LANE(15,30,31)
        LANE(16,32,33) LANE(17,34,35) LANE(18,36,37) LANE(19,38,39)
        LANE(20,40,41) LANE(21,42,43) LANE(22,44,45) LANE(23,46,47)
        LANE(24,48,49) LANE(25,50,51) LANE(26,52,53) LANE(27,54,55)
        LANE(28,56,57) LANE(29,58,59) LANE(30,60,61) LANE(31,62,63)
        LANE(32,64,65) LANE(33,66,67) LANE(34,68,69) LANE(35,70,71)
        LANE(36,72,73) LANE(37,74,75) LANE(38,76,77) LANE(39,78,79)
        LANE(40,80,81) LANE(41,82,83) LANE(42,84,85) LANE(43,86,87)
        LANE(44,88,89) LANE(45,90,91) LANE(46,92,93) LANE(47,94,95)

        TAILC(0) TAILC(1) TAILC(2) TAILC(3)
        TAILC(4) TAILC(5) TAILC(6) TAILC(7)

        const float z1 = a1 + a1b;
        const float z2 = a2 + a2b;

        if (t < 256) {
            // i, g -> p = sigmoid(i)*tanh(g)
            s_pbuf[t] = sigmoidf_(z1) * tanhf_(z2);
        }
        const float fg = sigmoidf_(z1);  // f (valid for t>=256)
        const float og = sigmoidf_(z2);  // o
        __syncthreads();
        if (t >= 256) {
            const int u = t - 256;
            c_state = fg * c_state + s_pbuf[u];
            h_last = og * tanhf_(c_state);
            ((__half*)hw)[u] = __float2half_rn(h_last);
        }
        __syncthreads();
        uint32_t* tmp = hr; hr = hw; hw = tmp;
    }

    if (t >= 256) h_out[b * HID + (t - 256)] = h_last;
}

// ---------- head: fc + relu + out + softmax ----------
__global__ void head_kernel(const float* __restrict__ fc_w,
                            const float* __restrict__ fc_b,
                            const float* __restrict__ out_w,
                            const float* __restrict__ out_b,
                            const float* __restrict__ convf,
                            const float* __restrict__ ksim,
                            const float* __restrict__ h_out,
                            float* __restrict__ out) {
    int b = blockIdx.x, j = threadIdx.x;  // 256 threads
    const float* hrow = h_out + b * HID;
    const float* w = fc_w + j * (HID + 2);
    float acc = fc_b[j] + w[0] * convf[b] + w[HID + 1] * ksim[b];
#pragma unroll 8
    for (int k = 0; k < HID; ++k) acc += w[1 + k] * hrow[k];
    float hid = fmaxf(acc, 0.f);
    __shared__ float r0[256], r1[256];
    r0[j] = hid * out_w[j];
    r1[j] = hid * out_w[HID + j];
    __syncthreads();
    for (int off = 128; off > 0; off >>= 1) {
        if (j < off) { r0[j] += r0[j + off]; r1[j] += r1[j + off]; }
        __syncthreads();
    }
    if (j == 0) {
        float l0 = r0[0] + out_b[0];
        float l1 = r1[0] + out_b[1];
        float m = fmaxf(l0, l1);
        float e0 = __expf(l0 - m), e1 = __expf(l1 - m);
        float inv = 1.0f / (e0 + e1);
        out[b * 2 + 0] = e0 * inv;
        out[b * 2 + 1] = e1 * inv;
    }
}

// ---------- launch ----------
extern "C" void kernel_launch(void* const* d_in, const int* in_sizes, int n_in,
                              void* d_out, int out_size, void* d_ws, size_t ws_size,
                              hipStream_t stream) {
    const float* x      = (const float*)d_in[0];
    const float* conv_w = (const float*)d_in[1];
    const float* conv_b = (const float*)d_in[2];
    const float* Wih    = (const float*)d_in[3];
    const float* Whh    = (const float*)d_in[4];
    const float* bih    = (const float*)d_in[5];
    const float* bhh    = (const float*)d_in[6];
    const float* fcw    = (const float*)d_in[7];
    const float* fcb    = (const float*)d_in[8];
    const float* outw   = (const float*)d_in[9];
    const float* outb   = (const float*)d_in[10];
    float* out = (float*)d_out;

    uint8_t* ws = (uint8_t*)d_ws;
    uint32_t* wreg  = (uint32_t*)ws;
    uint32_t* wtail = (uint32_t*)(ws + OFF_WTAIL);
    float* bias  = (float*)(ws + OFF_BIAS);
    float* convf = (float*)(ws + OFF_CONVF);
    float* ksim  = (float*)(ws + OFF_KSIM);
    float* h_out = (float*)(ws + OFF_HOUT);

    prep_kernel<<<512, 256, 0, stream>>>(Whh, bih, bhh, wreg, wtail, bias);
    feat_kernel<<<BATCH, 256, 0, stream>>>(x, conv_w, conv_b, convf, ksim);

    recur_kernel<<<BATCH, 512, 0, stream>>>(x, Wih, wreg, wtail, bias, h_out);

    head_kernel<<<BATCH, 256, 0, stream>>>(fcw, fcb, outw, outb, convf, ksim, h_out, out);
}